// Round 3
// baseline (3824.355 us; speedup 1.0000x reference)
//
#include <hip/hip_runtime.h>
#include <stdint.h>

// B=32, L=256, D=128. Reader LSTM scan + attention-memory writer scan.
// ALL inputs/outputs are FP32 (per reference setup_inputs dtypes).
// Inputs: x(32,256,128), Wr(128,512), Ur(128,512), br(512),
//         Ww(128,512), Uw(128,512), bw(512), Wc(256,128), bc(128)
// Output: final writer h (32,128) fp32.
//
// One block per batch element (32 blocks x 512 threads). mem register-
// resident in TWO layouts: row-major Mr (thread=(row,half): 32 f32-pairs)
// for score dots, col-major Mc (thread=(rowgroup,colpair)) for m_rt column
// sums; both updated with bit-identical lerp math. o_seq fp32 in global ws.
// Weights pre-transposed to fp32 float4 k-tiles for dwordx4 + v_pk_fma_f32.
// x_t@Wr computed in-loop against LDS-double-buffered x_t (prefetched in
// the gate phase; no extra syncs, no big XW workspace).

#define LL 256
#define NT 512

typedef float v2f __attribute__((ext_vector_type(2)));

__device__ __forceinline__ float hsig(float x) { return fminf(fmaxf(fmaf(x, 0.2f, 0.5f), 0.f), 1.f); }
__device__ __forceinline__ float tanh_fast(float x) {
  x = fminf(fmaxf(x, -15.f), 15.f);
  float e = __expf(2.f * x);
  return (e - 1.f) / (e + 1.f);
}

// ---- Prep: transpose fp32 W[K][J] (row-major) -> float4 k-tiles ----------
// dst float4 index (k>>2)*J + j holds rows k..k+3 of column j.
__global__ __launch_bounds__(512) void wtrans_kernel(const float* __restrict__ src,
                                                     float* __restrict__ dst, int jshift) {
  int idx = blockIdx.x * 512 + threadIdx.x;
  int J = 1 << jshift;
  int k = idx >> jshift, j = idx & (J - 1);
  dst[(((size_t)(k >> 2) << jshift) + j) * 4 + (k & 3)] = src[idx];
}

// ---- Fused sequential kernel ----------------------------------------------
__global__ __launch_bounds__(512, 2) void fused_kernel(
    const float* __restrict__ x,
    const float4* __restrict__ WrT4, const float4* __restrict__ UrT4,
    const float4* __restrict__ WwT4, const float4* __restrict__ UwT4,
    const float4* __restrict__ WcT4,
    const float* __restrict__ br, const float* __restrict__ bw,
    const float* __restrict__ bc,
    float* __restrict__ og, float* __restrict__ out) {
  alignas(16) __shared__ float x_s[2][128];
  alignas(16) __shared__ float h_s[128];
  alignas(16) __shared__ float osA[128], osB[128];
  alignas(16) __shared__ float sc_s[256], ee_s[256];
  alignas(16) __shared__ float mr_s[128], ct_s[128];
  alignas(16) __shared__ float pp_s[1024];
  __shared__ float rr_s[16];

  const int b = blockIdx.x, tid = threadIdx.x;
  const int lane = tid & 63, wv = tid >> 6;
  const int l = tid >> 1, hf = tid & 1;          // row-major role
  const int q = tid >> 6, dp = tid & 63;         // col-major role

  const float* xg = x + (size_t)b * (LL * 128);
  float* ogb = og + (size_t)b * (LL * 128);

  // ---- register-resident mem, two layouts (fp32 pairs) ----
  v2f Mr[32], Mc[32];
#pragma unroll
  for (int w = 0; w < 32; w++) Mr[w] = *(const v2f*)(xg + l * 128 + hf * 64 + 2 * w);
#pragma unroll
  for (int i = 0; i < 32; i++) Mc[i] = *(const v2f*)(xg + (q * 32 + i) * 128 + 2 * dp);

  const float brj = br[tid];
  const float bwj = bw[tid];
  const float bcj = (tid < 128) ? bc[tid] : 0.f;

  // ================= READER =================
  float c_r = 0.f;
  if (tid < 128) { h_s[tid] = 0.f; x_s[0][tid] = xg[tid]; }
  __syncthreads();
  for (int t = 0; t < LL; t++) {
    const float* xs = x_s[t & 1];
    v2f acc = {0.f, 0.f};
#pragma unroll 8
    for (int i4 = 0; i4 < 32; i4++) {
      float4 w4 = WrT4[i4 * 512 + tid];
      float4 v4 = *(const float4*)&xs[4 * i4];
      v2f a = {w4.x, w4.y}, va = {v4.x, v4.y};
      v2f b2 = {w4.z, w4.w}, vb = {v4.z, v4.w};
      acc += a * va;
      acc += b2 * vb;
    }
#pragma unroll 8
    for (int i4 = 0; i4 < 32; i4++) {
      float4 w4 = UrT4[i4 * 512 + tid];
      float4 v4 = *(const float4*)&h_s[4 * i4];
      v2f a = {w4.x, w4.y}, va = {v4.x, v4.y};
      v2f b2 = {w4.z, w4.w}, vb = {v4.z, v4.w};
      acc += a * va;
      acc += b2 * vb;
    }
    pp_s[tid] = acc.x + acc.y + brj;
    __syncthreads();
    if (tid < 128) {
      float zi = pp_s[tid], zf = pp_s[128 + tid], zg = pp_s[256 + tid], zo = pp_s[384 + tid];
      float ii = hsig(zi), ff = hsig(zf), gg = tanh_fast(zg), oo = hsig(zo);
      c_r = fmaf(ff, c_r, ii * gg);
      float h = oo * tanh_fast(c_r);
      h_s[tid] = h;
      ogb[t * 128 + tid] = h;
      if (t + 1 < LL) x_s[(t + 1) & 1][tid] = xg[(t + 1) * 128 + tid];
    }
    __syncthreads();
  }

  // ================= WRITER =================
  float c_w = 0.f;
  if (tid < 128) { h_s[tid] = 0.f; osA[tid] = ogb[tid]; }
  __syncthreads();
  { // prologue: sc_s[l] = mem0[l] . o_0
    v2f S = {0.f, 0.f};
#pragma unroll
    for (int w = 0; w < 32; w++) S += Mr[w] * (*(const v2f*)&osA[hf * 64 + 2 * w]);
    float s = S.x + S.y;
    s += __shfl_xor(s, 1);
    if (hf == 0) sc_s[l] = s;
  }
  __syncthreads();

  for (int t = 0; t < LL; t++) {
    // S1: publish o_t / o_{t+1}; softmax max
    if (tid < 128) osA[tid] = ogb[t * 128 + tid];
    else if (tid < 256 && t + 1 < LL) osB[tid - 128] = ogb[(t + 1) * 128 + (tid - 128)];
    if (tid < 256) {
      float m = sc_s[tid];
#pragma unroll
      for (int off = 32; off > 0; off >>= 1) m = fmaxf(m, __shfl_xor(m, off));
      if (lane == 0) rr_s[wv] = m;
    }
    __syncthreads();
    // S2: exp + sum
    if (tid < 256) {
      float mx = fmaxf(fmaxf(rr_s[0], rr_s[1]), fmaxf(rr_s[2], rr_s[3]));
      float e = __expf(sc_s[tid] - mx);
      ee_s[tid] = e;
      float s2 = e;
#pragma unroll
      for (int off = 32; off > 0; off >>= 1) s2 += __shfl_xor(s2, off);
      if (lane == 0) rr_s[8 + wv] = s2;
    }
    __syncthreads();
    const float inv = 1.f / (rr_s[8] + rr_s[9] + rr_s[10] + rr_s[11]);
    // S3: m_rt partials (col-major, register-local)
    {
      v2f P = {0.f, 0.f};
#pragma unroll
      for (int i = 0; i < 32; i++) P += Mc[i] * ee_s[q * 32 + i];
      *(v2f*)&pp_s[q * 128 + 2 * dp] = P;
    }
    __syncthreads();
    // S4: m_rt final
    if (tid < 128) {
      float s = 0.f;
#pragma unroll
      for (int g = 0; g < 8; g++) s += pp_s[g * 128 + tid];
      mr_s[tid] = s * inv;
    }
    __syncthreads();
    // S5: c_t partials = [o_t | m_rt] @ Wc
    {
      const int j = tid & 127, kq = tid >> 7;
      const float* in = (kq < 2) ? (osA + kq * 64) : (mr_s + (kq - 2) * 64);
      v2f A = {0.f, 0.f};
#pragma unroll
      for (int i4 = 0; i4 < 16; i4++) {
        float4 w4 = WcT4[(size_t)(kq * 16 + i4) * 128 + j];
        float4 v4 = *(const float4*)&in[4 * i4];
        v2f a = {w4.x, w4.y}, va = {v4.x, v4.y};
        v2f b2 = {w4.z, w4.w}, vb = {v4.z, v4.w};
        A += a * va;
        A += b2 * vb;
      }
      pp_s[kq * 128 + j] = A.x + A.y;
    }
    __syncthreads();
    // S6: c_t final
    if (tid < 128)
      ct_s[tid] = bcj + pp_s[tid] + pp_s[128 + tid] + pp_s[256 + tid] + pp_s[384 + tid];
    __syncthreads();
    // S7: z[j] = ct@Ww + h@Uw + bw
    {
      v2f A = {0.f, 0.f};
#pragma unroll 8
      for (int i4 = 0; i4 < 32; i4++) {
        float4 w4 = WwT4[i4 * 512 + tid];
        float4 v4 = *(const float4*)&ct_s[4 * i4];
        v2f a = {w4.x, w4.y}, va = {v4.x, v4.y};
        v2f b2 = {w4.z, w4.w}, vb = {v4.z, v4.w};
        A += a * va;
        A += b2 * vb;
      }
#pragma unroll 8
      for (int i4 = 0; i4 < 32; i4++) {
        float4 w4 = UwT4[i4 * 512 + tid];
        float4 v4 = *(const float4*)&h_s[4 * i4];
        v2f a = {w4.x, w4.y}, va = {v4.x, v4.y};
        v2f b2 = {w4.z, w4.w}, vb = {v4.z, v4.w};
        A += a * va;
        A += b2 * vb;
      }
      pp_s[tid] = A.x + A.y + bwj;
    }
    __syncthreads();
    // S8: gates
    if (tid < 128) {
      float zi = pp_s[tid], zf = pp_s[128 + tid], zg = pp_s[256 + tid], zo = pp_s[384 + tid];
      float ii = hsig(zi), ff = hsig(zf), gg = tanh_fast(zg), oo = hsig(zo);
      c_w = fmaf(ff, c_w, ii * gg);
      float h = oo * tanh_fast(c_w);
      h_s[tid] = h;
    }
    __syncthreads();
    // S9: mem update (both layouts, identical math) + fused next scores
    if (t + 1 < LL) {
      const float zr = ee_s[l] * inv;
      v2f S = {0.f, 0.f};
#pragma unroll
      for (int w = 0; w < 32; w++) {
        v2f h2 = *(const v2f*)&h_s[hf * 64 + 2 * w];
        v2f m = Mr[w];
        v2f n = m + (h2 - m) * zr;
        Mr[w] = n;
        S += n * (*(const v2f*)&osB[hf * 64 + 2 * w]);
      }
      float s = S.x + S.y;
      s += __shfl_xor(s, 1);
      if (hf == 0) sc_s[l] = s;
      v2f hc = *(const v2f*)&h_s[2 * dp];
#pragma unroll
      for (int i = 0; i < 32; i++) {
        float zc = ee_s[q * 32 + i] * inv;
        v2f m = Mc[i];
        Mc[i] = m + (hc - m) * zc;
      }
    }
    __syncthreads();
  }

  if (tid < 128) out[b * 128 + tid] = h_s[tid];
}

extern "C" void kernel_launch(void* const* d_in, const int* in_sizes, int n_in,
                              void* d_out, int out_size, void* d_ws, size_t ws_size,
                              hipStream_t stream) {
  const float* x  = (const float*)d_in[0];
  const float* Wr = (const float*)d_in[1];
  const float* Ur = (const float*)d_in[2];
  const float* br = (const float*)d_in[3];
  const float* Ww = (const float*)d_in[4];
  const float* Uw = (const float*)d_in[5];
  const float* bw = (const float*)d_in[6];
  const float* Wc = (const float*)d_in[7];
  const float* bc = (const float*)d_in[8];
  float* out = (float*)d_out;

  // workspace (floats): og 1,048,576 | WrT 65,536 | UrT 65,536 | WwT 65,536 |
  // UwT 65,536 | WcT 32,768  -> ~5.3 MB total
  float* og  = (float*)d_ws;
  float* WrT = og + 1048576;
  float* UrT = WrT + 65536;
  float* WwT = UrT + 65536;
  float* UwT = WwT + 65536;
  float* WcT = UwT + 65536;

  wtrans_kernel<<<128, 512, 0, stream>>>(Wr, WrT, 9);
  wtrans_kernel<<<128, 512, 0, stream>>>(Ur, UrT, 9);
  wtrans_kernel<<<128, 512, 0, stream>>>(Ww, WwT, 9);
  wtrans_kernel<<<128, 512, 0, stream>>>(Uw, UwT, 9);
  wtrans_kernel<<<64, 512, 0, stream>>>(Wc, WcT, 7);
  fused_kernel<<<32, NT, 0, stream>>>(x, (const float4*)WrT, (const float4*)UrT,
                                      (const float4*)WwT, (const float4*)UwT,
                                      (const float4*)WcT, br, bw, bc, og, out);
}